// Round 4
// baseline (404.297 us; speedup 1.0000x reference)
//
#include <hip/hip_runtime.h>
#include <hip/hip_bf16.h>

// NeuralNetwork_85255100825763
// conv1+bn+relu+pool -> conv2+bn+relu+pool -> MLP+softmax gate
// -> 8x LSTM(128) over 256 steps -> gated mean -> output proj.
// LSTM v4: 256 blocks x 512 threads (1 block/CU). Thread owns a FULL
// 128-float gate row in 32 named float4 regs, made OPAQUE via empty
// inline-asm "+v" so the compiler cannot rematerialize the loads
// inside the loop (Rounds 0/2 failure mode: VGPR=84/88, weights
// re-fetched through L1 every step -> 437us L1-BW wall).
// h reads are all-lane broadcast ds_read_b128 (0 bank conflicts).

typedef float v4f __attribute__((ext_vector_type(4)));

__device__ __forceinline__ float sigmoidf_(float x) {
    return 1.0f / (1.0f + __expf(-x));
}
__device__ __forceinline__ float tanhf_(float x) {
    float t = __expf(-2.0f * fabsf(x));   // in (0,1], no overflow
    float r = (1.0f - t) / (1.0f + t);
    return copysignf(r, x);
}

// ---------------- Kernel 1: conv1 + bn1 + relu + maxpool2 -> c1 (64,16,64,64)
__global__ __launch_bounds__(256) void k_conv1(
    const float* __restrict__ x, const float* __restrict__ w,
    const float* __restrict__ cb, const float* __restrict__ g,
    const float* __restrict__ bb, const float* __restrict__ m,
    const float* __restrict__ v, float* __restrict__ c1)
{
    __shared__ __align__(16) float w1s[192];
    __shared__ float As[16], Cs[16];
    int tid = threadIdx.x;
    if (tid < 192) w1s[tid] = w[tid];
    if (tid < 16) {
        float s = g[tid] / sqrtf(v[tid] + 1e-5f);
        As[tid] = s;
        Cs[tid] = (cb[tid] - m[tid]) * s + bb[tid];
    }
    __syncthreads();

    int gid = blockIdx.x * 256 + tid;
    int b   = gid >> 12;
    int rem = gid & 4095;
    int oi  = rem >> 6, oj = rem & 63;

    float xr[3][4][4];
    #pragma unroll
    for (int ci = 0; ci < 3; ++ci) {
        #pragma unroll
        for (int r = 0; r < 4; ++r) {
            const float4 t4 = *(const float4*)(x +
                (((size_t)(b * 3 + ci) * 256 + (4 * oi + r)) * 256 + 4 * oj));
            xr[ci][r][0] = t4.x; xr[ci][r][1] = t4.y;
            xr[ci][r][2] = t4.z; xr[ci][r][3] = t4.w;
        }
    }
    const float4* w4 = (const float4*)w1s;
    #pragma unroll
    for (int co = 0; co < 16; ++co) {
        float val[2][2] = {{0.f, 0.f}, {0.f, 0.f}};
        #pragma unroll
        for (int ci = 0; ci < 3; ++ci) {
            float4 wq = w4[co * 3 + ci];
            #pragma unroll
            for (int pi = 0; pi < 2; ++pi) {
                #pragma unroll
                for (int pj = 0; pj < 2; ++pj) {
                    float a = val[pi][pj];
                    a = fmaf(xr[ci][2*pi  ][2*pj  ], wq.x, a);
                    a = fmaf(xr[ci][2*pi  ][2*pj+1], wq.y, a);
                    a = fmaf(xr[ci][2*pi+1][2*pj  ], wq.z, a);
                    a = fmaf(xr[ci][2*pi+1][2*pj+1], wq.w, a);
                    val[pi][pj] = a;
                }
            }
        }
        float A = As[co], C = Cs[co];
        float mx = 0.0f;
        #pragma unroll
        for (int pi = 0; pi < 2; ++pi)
            #pragma unroll
            for (int pj = 0; pj < 2; ++pj)
                mx = fmaxf(mx, fmaf(A, val[pi][pj], C));
        c1[((size_t)(b * 16 + co) * 64 + oi) * 64 + oj] = mx;
    }
}

// ---------------- Kernel 2: conv2 + bn2 + relu + maxpool2 -> c (64,256)
__global__ __launch_bounds__(256) void k_conv2(
    const float* __restrict__ c1, const float* __restrict__ w2,
    const float* __restrict__ cb, const float* __restrict__ g,
    const float* __restrict__ bb, const float* __restrict__ m,
    const float* __restrict__ v, float* __restrict__ c)
{
    __shared__ float w2s[64];
    int tid = threadIdx.x;
    if (tid < 64) w2s[tid] = w2[tid];
    __syncthreads();
    float A2 = g[0] / sqrtf(v[0] + 1e-5f);
    float C2 = (cb[0] - m[0]) * A2 + bb[0];

    int gid = blockIdx.x * 256 + tid;
    int b   = gid >> 8;
    int rem = gid & 255;
    int oi  = rem >> 4, oj = rem & 15;

    float val[2][2] = {{0.f, 0.f}, {0.f, 0.f}};
    for (int ci = 0; ci < 16; ++ci) {
        float xr[4][4];
        #pragma unroll
        for (int r = 0; r < 4; ++r) {
            float4 t4 = *(const float4*)(c1 +
                (((size_t)(b * 16 + ci) * 64 + (4 * oi + r)) * 64 + 4 * oj));
            xr[r][0] = t4.x; xr[r][1] = t4.y; xr[r][2] = t4.z; xr[r][3] = t4.w;
        }
        float w0 = w2s[ci*4+0], w1 = w2s[ci*4+1], w2v = w2s[ci*4+2], w3 = w2s[ci*4+3];
        #pragma unroll
        for (int pi = 0; pi < 2; ++pi) {
            #pragma unroll
            for (int pj = 0; pj < 2; ++pj) {
                float a = val[pi][pj];
                a = fmaf(xr[2*pi  ][2*pj  ], w0, a);
                a = fmaf(xr[2*pi  ][2*pj+1], w1, a);
                a = fmaf(xr[2*pi+1][2*pj  ], w2v, a);
                a = fmaf(xr[2*pi+1][2*pj+1], w3, a);
                val[pi][pj] = a;
            }
        }
    }
    float mx = 0.0f;
    #pragma unroll
    for (int pi = 0; pi < 2; ++pi)
        #pragma unroll
        for (int pj = 0; pj < 2; ++pj)
            mx = fmaxf(mx, fmaf(A2, val[pi][pj], C2));
    c[(size_t)b * 256 + oi * 16 + oj] = mx;
}

// ---------------- Kernel 3: MLP + softmax -> S (64,8) row-major flat
__global__ __launch_bounds__(64) void k_mlp(
    const float* __restrict__ c,
    const float* __restrict__ w1, const float* __restrict__ b1,
    const float* __restrict__ w2, const float* __restrict__ b2,
    const float* __restrict__ w3, const float* __restrict__ b3,
    float* __restrict__ S)
{
    __shared__ __align__(16) float cs[256];
    __shared__ float h1s[32], h2s[32], ls[8];
    int b = blockIdx.x, tid = threadIdx.x;
    *(float4*)&cs[tid * 4] = *(const float4*)(c + (size_t)b * 256 + tid * 4);
    __syncthreads();
    if (tid < 32) {
        float acc = b1[tid];
        for (int k = 0; k < 256; ++k) acc = fmaf(cs[k], w1[tid * 256 + k], acc);
        h1s[tid] = fmaxf(acc, 0.f);
    }
    __syncthreads();
    if (tid < 32) {
        float acc = b2[tid];
        #pragma unroll
        for (int k = 0; k < 32; ++k) acc = fmaf(h1s[k], w2[tid * 32 + k], acc);
        h2s[tid] = fmaxf(acc, 0.f);
    }
    __syncthreads();
    if (tid < 8) {
        float acc = b3[tid];
        #pragma unroll
        for (int k = 0; k < 32; ++k) acc = fmaf(h2s[k], w3[tid * 32 + k], acc);
        ls[tid] = acc;
    }
    __syncthreads();
    if (tid == 0) {
        float mx = ls[0];
        #pragma unroll
        for (int k = 1; k < 8; ++k) mx = fmaxf(mx, ls[k]);
        float e[8]; float sum = 0.f;
        #pragma unroll
        for (int k = 0; k < 8; ++k) { e[k] = expf(ls[k] - mx); sum += e[k]; }
        float inv = 1.0f / sum;
        #pragma unroll
        for (int k = 0; k < 8; ++k) S[b * 8 + k] = e[k] * inv;
    }
}

// ---------------- Kernel 4: LSTM, 256 steps. Block = (class, 2 batch rows).
// Thread owns whh[tid][0..127] in 32 OPAQUE (asm-pinned) float4 registers.
__global__ __launch_bounds__(512)
__attribute__((amdgpu_waves_per_eu(2, 2)))
void k_lstm(
    const float* __restrict__ whh, const float* __restrict__ wih,
    const float* __restrict__ bih, const float* __restrict__ bhh,
    const float* __restrict__ hn,  const float* __restrict__ c,
    float* __restrict__ lasth)
{
    __shared__ __align__(16) float h_lds[2][128];
    __shared__ float g_lds[2][512];
    __shared__ __align__(16) float c_lds[2][256];

    int tid   = threadIdx.x;
    int kcls  = blockIdx.x >> 5;
    int bbase = (blockIdx.x & 31) * 2;

    const v4f* wp = (const v4f*)(whh + ((size_t)(kcls * 512 + tid)) * 128);
    v4f wv0  = wp[0],  wv1  = wp[1],  wv2  = wp[2],  wv3  = wp[3];
    v4f wv4  = wp[4],  wv5  = wp[5],  wv6  = wp[6],  wv7  = wp[7];
    v4f wv8  = wp[8],  wv9  = wp[9],  wv10 = wp[10], wv11 = wp[11];
    v4f wv12 = wp[12], wv13 = wp[13], wv14 = wp[14], wv15 = wp[15];
    v4f wv16 = wp[16], wv17 = wp[17], wv18 = wp[18], wv19 = wp[19];
    v4f wv20 = wp[20], wv21 = wp[21], wv22 = wp[22], wv23 = wp[23];
    v4f wv24 = wp[24], wv25 = wp[25], wv26 = wp[26], wv27 = wp[27];
    v4f wv28 = wp[28], wv29 = wp[29], wv30 = wp[30], wv31 = wp[31];

    // Opacity barrier: the compiler cannot rematerialize these from memory
    // inside the loop; with the waves_per_eu(2,2) 256-VGPR budget it has no
    // reason to spill them either -> guaranteed register residency.
    asm volatile("" : "+v"(wv0),  "+v"(wv1),  "+v"(wv2),  "+v"(wv3),
                      "+v"(wv4),  "+v"(wv5),  "+v"(wv6),  "+v"(wv7));
    asm volatile("" : "+v"(wv8),  "+v"(wv9),  "+v"(wv10), "+v"(wv11),
                      "+v"(wv12), "+v"(wv13), "+v"(wv14), "+v"(wv15));
    asm volatile("" : "+v"(wv16), "+v"(wv17), "+v"(wv18), "+v"(wv19),
                      "+v"(wv20), "+v"(wv21), "+v"(wv22), "+v"(wv23));
    asm volatile("" : "+v"(wv24), "+v"(wv25), "+v"(wv26), "+v"(wv27),
                      "+v"(wv28), "+v"(wv29), "+v"(wv30), "+v"(wv31));

    float xw   = wih[kcls * 512 + tid];
    float bias = bih[kcls * 512 + tid] + bhh[kcls * 512 + tid];

    if (tid < 256) {
        int b = tid >> 7, j = tid & 127;
        h_lds[b][j] = hn[((size_t)kcls * 64 + bbase + b) * 128 + j];
    }
    if (tid < 128) {
        int f = tid * 4; int b = f >> 8; int off = f & 255;
        *(float4*)&c_lds[b][off] = *(const float4*)(c + (size_t)(bbase + b) * 256 + off);
    }
    float cc = 0.0f;
    __syncthreads();

// one float4 weight group: rows 0/1 broadcast-read, alternating acc chains
#define WSTEP(I, A0, A1)                                                        \
    {                                                                           \
        v4f h0 = *(const v4f*)&h_lds[0][4 * (I)];                               \
        v4f h1 = *(const v4f*)&h_lds[1][4 * (I)];                               \
        A0 = fmaf(wv##I[0], h0[0], A0); A1 = fmaf(wv##I[0], h1[0], A1);         \
        A0 = fmaf(wv##I[1], h0[1], A0); A1 = fmaf(wv##I[1], h1[1], A1);         \
        A0 = fmaf(wv##I[2], h0[2], A0); A1 = fmaf(wv##I[2], h1[2], A1);         \
        A0 = fmaf(wv##I[3], h0[3], A0); A1 = fmaf(wv##I[3], h1[3], A1);         \
    }

    for (int t = 0; t < 256; ++t) {
        float a0 = fmaf(c_lds[0][t], xw, bias);
        float a1 = fmaf(c_lds[1][t], xw, bias);
        float b0 = 0.0f, b1 = 0.0f;   // second pair of dep chains
        WSTEP(0,  a0, a1) WSTEP(1,  b0, b1) WSTEP(2,  a0, a1) WSTEP(3,  b0, b1)
        WSTEP(4,  a0, a1) WSTEP(5,  b0, b1) WSTEP(6,  a0, a1) WSTEP(7,  b0, b1)
        WSTEP(8,  a0, a1) WSTEP(9,  b0, b1) WSTEP(10, a0, a1) WSTEP(11, b0, b1)
        WSTEP(12, a0, a1) WSTEP(13, b0, b1) WSTEP(14, a0, a1) WSTEP(15, b0, b1)
        WSTEP(16, a0, a1) WSTEP(17, b0, b1) WSTEP(18, a0, a1) WSTEP(19, b0, b1)
        WSTEP(20, a0, a1) WSTEP(21, b0, b1) WSTEP(22, a0, a1) WSTEP(23, b0, b1)
        WSTEP(24, a0, a1) WSTEP(25, b0, b1) WSTEP(26, a0, a1) WSTEP(27, b0, b1)
        WSTEP(28, a0, a1) WSTEP(29, b0, b1) WSTEP(30, a0, a1) WSTEP(31, b0, b1)
        g_lds[0][tid] = a0 + b0;
        g_lds[1][tid] = a1 + b1;
        __syncthreads();   // gates visible; all h reads done

        if (tid < 256) {
            int b = tid >> 7, j = tid & 127;
            float gi = sigmoidf_(g_lds[b][j]);
            float gf = sigmoidf_(g_lds[b][128 + j]);
            float gg = tanhf_(g_lds[b][256 + j]);
            float go = sigmoidf_(g_lds[b][384 + j]);
            cc = gf * cc + gi * gg;
            float h = go * tanhf_(cc);
            h_lds[b][j] = h;
            if (j == 127)
                lasth[((size_t)kcls * 64 + bbase + b) * 256 + t] = h;
        }
        __syncthreads();   // new h visible
    }
#undef WSTEP
}

// ---------------- Kernel 5: gated mean over classes + output projection
__global__ __launch_bounds__(256) void k_out(
    const float* __restrict__ lasth, const float* __restrict__ S,
    const float* __restrict__ out_w, const float* __restrict__ out_b,
    float* __restrict__ out)
{
    __shared__ __align__(16) float avg[256];
    int b = blockIdx.x, t = threadIdx.x;
    float a = 0.f;
    #pragma unroll
    for (int k = 0; k < 8; ++k) {
        // pre.reshape(NCLS,B,1): weight(k,b) = S_flat[k*64+b]
        a = fmaf(S[k * 64 + b], lasth[((size_t)k * 64 + b) * 256 + t], a);
    }
    avg[t] = a * 0.125f;
    __syncthreads();
    if (t < 8) {
        float acc = out_b[t];
        for (int tt = 0; tt < 256; ++tt)
            acc = fmaf(avg[tt], out_w[t * 256 + tt], acc);
        out[b * 8 + t] = acc;
    }
}

extern "C" void kernel_launch(void* const* d_in, const int* in_sizes, int n_in,
                              void* d_out, int out_size, void* d_ws, size_t ws_size,
                              hipStream_t stream) {
    const float* x       = (const float*)d_in[0];
    const float* conv1_w = (const float*)d_in[1];
    const float* conv1_b = (const float*)d_in[2];
    const float* bn1_g   = (const float*)d_in[3];
    const float* bn1_b   = (const float*)d_in[4];
    const float* bn1_m   = (const float*)d_in[5];
    const float* bn1_v   = (const float*)d_in[6];
    const float* conv2_w = (const float*)d_in[7];
    const float* conv2_b = (const float*)d_in[8];
    const float* bn2_g   = (const float*)d_in[9];
    const float* bn2_b   = (const float*)d_in[10];
    const float* bn2_m   = (const float*)d_in[11];
    const float* bn2_v   = (const float*)d_in[12];
    const float* pre_w1  = (const float*)d_in[13];
    const float* pre_b1  = (const float*)d_in[14];
    const float* pre_w2  = (const float*)d_in[15];
    const float* pre_b2  = (const float*)d_in[16];
    const float* pre_w3  = (const float*)d_in[17];
    const float* pre_b3  = (const float*)d_in[18];
    const float* lstm_wih = (const float*)d_in[19];
    const float* lstm_whh = (const float*)d_in[20];
    const float* lstm_bih = (const float*)d_in[21];
    const float* lstm_bhh = (const float*)d_in[22];
    const float* hn      = (const float*)d_in[23];
    const float* out_w   = (const float*)d_in[24];
    const float* out_b   = (const float*)d_in[25];

    float* ws    = (float*)d_ws;
    float* c1    = ws;                       // 64*16*64*64 = 4194304
    float* c     = c1 + 4194304;             // 64*256      = 16384
    float* S     = c + 16384;                // 64*8        = 512
    float* lasth = S + 512;                  // 8*64*256    = 131072

    k_conv1<<<1024, 256, 0, stream>>>(x, conv1_w, conv1_b, bn1_g, bn1_b, bn1_m, bn1_v, c1);
    k_conv2<<<64, 256, 0, stream>>>(c1, conv2_w, conv2_b, bn2_g, bn2_b, bn2_m, bn2_v, c);
    k_mlp<<<64, 64, 0, stream>>>(c, pre_w1, pre_b1, pre_w2, pre_b2, pre_w3, pre_b3, S);
    k_lstm<<<256, 512, 0, stream>>>(lstm_whh, lstm_wih, lstm_bih, lstm_bhh, hn, c, lasth);
    k_out<<<64, 256, 0, stream>>>(lasth, S, out_w, out_b, (float*)d_out);
}

// Round 6
// 296.324 us; speedup vs baseline: 1.3644x; 1.3644x over previous
//
#include <hip/hip_runtime.h>
#include <hip/hip_bf16.h>
#include <hip/hip_fp16.h>

// NeuralNetwork_85255100825763
// conv1+bn+relu+pool -> conv2+bn+relu+pool -> MLP+softmax gate
// -> 8x LSTM(128) over 256 steps -> gated mean -> output proj.
//
// LSTM v6 (= v5 with compile fix): Rounds 0/2/4 were L2-BW-bound (16.8 GB
// weight re-reads / 437us = 38 TB/s = L2 ceiling) because the RA caps at
// ~88 VGPRs and spills the 128-float fp32 weight row. Fix: fp16 weights ->
// 64 VGPRs (16x packed u32x4 ext-vectors; ext_vector_type is required for
// "+v" inline-asm pinning — HIP's struct uint4 is rejected). Inner loop:
// v_dot2_f32_f16 (fp32 accumulate), h in LDS as packed fp16 (broadcast
// ds_read_b128, 0 conflicts). Gate activations fused into the all-thread
// GEMV phase (wave-uniform branch).

typedef _Float16 h2_t __attribute__((ext_vector_type(2)));
typedef unsigned int u32x4 __attribute__((ext_vector_type(4)));

__device__ __forceinline__ float dot2f(unsigned int w, unsigned int h, float acc) {
    return __builtin_amdgcn_fdot2(__builtin_bit_cast(h2_t, w),
                                  __builtin_bit_cast(h2_t, h), acc, false);
}
__device__ __forceinline__ float sigmoidf_(float x) {
    return 1.0f / (1.0f + __expf(-x));
}
__device__ __forceinline__ float tanhf_(float x) {
    float t = __expf(-2.0f * fabsf(x));   // in (0,1], no overflow
    float r = (1.0f - t) / (1.0f + t);
    return copysignf(r, x);
}
__device__ __forceinline__ unsigned short f2h(float x) {
    __half h = __float2half(x);           // RTNE
    return *(unsigned short*)&h;
}

// ---------------- Kernel 0: whh fp32 -> packed fp16 pairs (uint)
__global__ __launch_bounds__(256) void k_cvt(
    const float* __restrict__ w, unsigned int* __restrict__ wh)
{
    int i = blockIdx.x * 256 + threadIdx.x;     // 262144 pairs
    float2 f = ((const float2*)w)[i];
    unsigned short lo = f2h(f.x), hi = f2h(f.y);
    wh[i] = ((unsigned int)hi << 16) | lo;
}

// ---------------- Kernel 1: conv1 + bn1 + relu + maxpool2 -> c1 (64,16,64,64)
__global__ __launch_bounds__(256) void k_conv1(
    const float* __restrict__ x, const float* __restrict__ w,
    const float* __restrict__ cb, const float* __restrict__ g,
    const float* __restrict__ bb, const float* __restrict__ m,
    const float* __restrict__ v, float* __restrict__ c1)
{
    __shared__ __align__(16) float w1s[192];
    __shared__ float As[16], Cs[16];
    int tid = threadIdx.x;
    if (tid < 192) w1s[tid] = w[tid];
    if (tid < 16) {
        float s = g[tid] / sqrtf(v[tid] + 1e-5f);
        As[tid] = s;
        Cs[tid] = (cb[tid] - m[tid]) * s + bb[tid];
    }
    __syncthreads();

    int gid = blockIdx.x * 256 + tid;
    int b   = gid >> 12;
    int rem = gid & 4095;
    int oi  = rem >> 6, oj = rem & 63;

    float xr[3][4][4];
    #pragma unroll
    for (int ci = 0; ci < 3; ++ci) {
        #pragma unroll
        for (int r = 0; r < 4; ++r) {
            const float4 t4 = *(const float4*)(x +
                (((size_t)(b * 3 + ci) * 256 + (4 * oi + r)) * 256 + 4 * oj));
            xr[ci][r][0] = t4.x; xr[ci][r][1] = t4.y;
            xr[ci][r][2] = t4.z; xr[ci][r][3] = t4.w;
        }
    }
    const float4* w4 = (const float4*)w1s;
    #pragma unroll
    for (int co = 0; co < 16; ++co) {
        float val[2][2] = {{0.f, 0.f}, {0.f, 0.f}};
        #pragma unroll
        for (int ci = 0; ci < 3; ++ci) {
            float4 wq = w4[co * 3 + ci];
            #pragma unroll
            for (int pi = 0; pi < 2; ++pi) {
                #pragma unroll
                for (int pj = 0; pj < 2; ++pj) {
                    float a = val[pi][pj];
                    a = fmaf(xr[ci][2*pi  ][2*pj  ], wq.x, a);
                    a = fmaf(xr[ci][2*pi  ][2*pj+1], wq.y, a);
                    a = fmaf(xr[ci][2*pi+1][2*pj  ], wq.z, a);
                    a = fmaf(xr[ci][2*pi+1][2*pj+1], wq.w, a);
                    val[pi][pj] = a;
                }
            }
        }
        float A = As[co], C = Cs[co];
        float mx = 0.0f;
        #pragma unroll
        for (int pi = 0; pi < 2; ++pi)
            #pragma unroll
            for (int pj = 0; pj < 2; ++pj)
                mx = fmaxf(mx, fmaf(A, val[pi][pj], C));
        c1[((size_t)(b * 16 + co) * 64 + oi) * 64 + oj] = mx;
    }
}

// ---------------- Kernel 2: conv2 + bn2 + relu + maxpool2 -> c (64,256)
__global__ __launch_bounds__(256) void k_conv2(
    const float* __restrict__ c1, const float* __restrict__ w2,
    const float* __restrict__ cb, const float* __restrict__ g,
    const float* __restrict__ bb, const float* __restrict__ m,
    const float* __restrict__ v, float* __restrict__ c)
{
    __shared__ float w2s[64];
    int tid = threadIdx.x;
    if (tid < 64) w2s[tid] = w2[tid];
    __syncthreads();
    float A2 = g[0] / sqrtf(v[0] + 1e-5f);
    float C2 = (cb[0] - m[0]) * A2 + bb[0];

    int gid = blockIdx.x * 256 + tid;
    int b   = gid >> 8;
    int rem = gid & 255;
    int oi  = rem >> 4, oj = rem & 15;

    float val[2][2] = {{0.f, 0.f}, {0.f, 0.f}};
    for (int ci = 0; ci < 16; ++ci) {
        float xr[4][4];
        #pragma unroll
        for (int r = 0; r < 4; ++r) {
            float4 t4 = *(const float4*)(c1 +
                (((size_t)(b * 16 + ci) * 64 + (4 * oi + r)) * 64 + 4 * oj));
            xr[r][0] = t4.x; xr[r][1] = t4.y; xr[r][2] = t4.z; xr[r][3] = t4.w;
        }
        float w0 = w2s[ci*4+0], w1 = w2s[ci*4+1], w2v = w2s[ci*4+2], w3 = w2s[ci*4+3];
        #pragma unroll
        for (int pi = 0; pi < 2; ++pi) {
            #pragma unroll
            for (int pj = 0; pj < 2; ++pj) {
                float a = val[pi][pj];
                a = fmaf(xr[2*pi  ][2*pj  ], w0, a);
                a = fmaf(xr[2*pi  ][2*pj+1], w1, a);
                a = fmaf(xr[2*pi+1][2*pj  ], w2v, a);
                a = fmaf(xr[2*pi+1][2*pj+1], w3, a);
                val[pi][pj] = a;
            }
        }
    }
    float mx = 0.0f;
    #pragma unroll
    for (int pi = 0; pi < 2; ++pi)
        #pragma unroll
        for (int pj = 0; pj < 2; ++pj)
            mx = fmaxf(mx, fmaf(A2, val[pi][pj], C2));
    c[(size_t)b * 256 + oi * 16 + oj] = mx;
}

// ---------------- Kernel 3: MLP + softmax -> S (64,8) row-major flat
__global__ __launch_bounds__(64) void k_mlp(
    const float* __restrict__ c,
    const float* __restrict__ w1, const float* __restrict__ b1,
    const float* __restrict__ w2, const float* __restrict__ b2,
    const float* __restrict__ w3, const float* __restrict__ b3,
    float* __restrict__ S)
{
    __shared__ __align__(16) float cs[256];
    __shared__ float h1s[32], h2s[32], ls[8];
    int b = blockIdx.x, tid = threadIdx.x;
    *(float4*)&cs[tid * 4] = *(const float4*)(c + (size_t)b * 256 + tid * 4);
    __syncthreads();
    if (tid < 32) {
        float acc = b1[tid];
        for (int k = 0; k < 256; ++k) acc = fmaf(cs[k], w1[tid * 256 + k], acc);
        h1s[tid] = fmaxf(acc, 0.f);
    }
    __syncthreads();
    if (tid < 32) {
        float acc = b2[tid];
        #pragma unroll
        for (int k = 0; k < 32; ++k) acc = fmaf(h1s[k], w2[tid * 32 + k], acc);
        h2s[tid] = fmaxf(acc, 0.f);
    }
    __syncthreads();
    if (tid < 8) {
        float acc = b3[tid];
        #pragma unroll
        for (int k = 0; k < 32; ++k) acc = fmaf(h2s[k], w3[tid * 32 + k], acc);
        ls[tid] = acc;
    }
    __syncthreads();
    if (tid == 0) {
        float mx = ls[0];
        #pragma unroll
        for (int k = 1; k < 8; ++k) mx = fmaxf(mx, ls[k]);
        float e[8]; float sum = 0.f;
        #pragma unroll
        for (int k = 0; k < 8; ++k) { e[k] = expf(ls[k] - mx); sum += e[k]; }
        float inv = 1.0f / sum;
        #pragma unroll
        for (int k = 0; k < 8; ++k) S[b * 8 + k] = e[k] * inv;
    }
}

// ---------------- Kernel 4: LSTM, 256 steps. Block = (class, 2 batch rows).
// Thread owns whh[tid][0..127] as fp16 pairs in 16 u32x4 (= 64 VGPRs).
__global__
__attribute__((amdgpu_flat_work_group_size(512, 512), amdgpu_waves_per_eu(1, 2)))
void k_lstm(
    const unsigned int* __restrict__ whh_h, const float* __restrict__ wih,
    const float* __restrict__ bih, const float* __restrict__ bhh,
    const float* __restrict__ hn,  const float* __restrict__ c,
    float* __restrict__ lasth)
{
    __shared__ __align__(16) unsigned short h_h[2][128];   // h as fp16
    __shared__ float g_lds[2][512];                        // activated gates
    __shared__ __align__(16) float c_lds[2][256];

    int tid   = threadIdx.x;
    int kcls  = blockIdx.x >> 5;
    int bbase = (blockIdx.x & 31) * 2;

    // 128 fp16 weights = 16 u32x4 = 64 VGPRs (ext-vector -> "+v" legal)
    const u32x4* wp = (const u32x4*)(whh_h + ((size_t)(kcls * 512 + tid)) * 64);
    u32x4 u0  = wp[0],  u1  = wp[1],  u2  = wp[2],  u3  = wp[3];
    u32x4 u4  = wp[4],  u5  = wp[5],  u6  = wp[6],  u7  = wp[7];
    u32x4 u8  = wp[8],  u9  = wp[9],  u10 = wp[10], u11 = wp[11];
    u32x4 u12 = wp[12], u13 = wp[13], u14 = wp[14], u15 = wp[15];
    asm volatile("" : "+v"(u0), "+v"(u1), "+v"(u2),  "+v"(u3),
                      "+v"(u4), "+v"(u5), "+v"(u6),  "+v"(u7));
    asm volatile("" : "+v"(u8), "+v"(u9), "+v"(u10), "+v"(u11),
                      "+v"(u12),"+v"(u13),"+v"(u14), "+v"(u15));

    float xw   = wih[kcls * 512 + tid];
    float bias = bih[kcls * 512 + tid] + bhh[kcls * 512 + tid];
    int gtype  = tid >> 7;   // 0=i 1=f 2=g 3=o (wave-uniform)

    if (tid < 256) {
        int b = tid >> 7, j = tid & 127;
        h_h[b][j] = f2h(hn[((size_t)kcls * 64 + bbase + b) * 128 + j]);
    }
    if (tid < 128) {
        int f = tid * 4; int b = f >> 8; int off = f & 255;
        *(float4*)&c_lds[b][off] = *(const float4*)(c + (size_t)(bbase + b) * 256 + off);
    }
    float cc = 0.0f;
    __syncthreads();

    const u32x4* hq0 = (const u32x4*)&h_h[0][0];   // 16B = 8 fp16 h values
    const u32x4* hq1 = (const u32x4*)&h_h[1][0];

// one u32x4 weight group (8 halves) vs both batch rows; 2 chains per row
#define DSTEP(I, A0, A1, B0, B1)                                        \
    {                                                                   \
        u32x4 q0 = hq0[I]; u32x4 q1 = hq1[I];                           \
        A0 = dot2f(u##I[0], q0[0], A0); A1 = dot2f(u##I[0], q1[0], A1); \
        B0 = dot2f(u##I[1], q0[1], B0); B1 = dot2f(u##I[1], q1[1], B1); \
        A0 = dot2f(u##I[2], q0[2], A0); A1 = dot2f(u##I[2], q1[2], A1); \
        B0 = dot2f(u##I[3], q0[3], B0); B1 = dot2f(u##I[3], q1[3], B1); \
    }

    for (int t = 0; t < 256; ++t) {
        float a0 = fmaf(c_lds[0][t], xw, bias);
        float a1 = fmaf(c_lds[1][t], xw, bias);
        float b0 = 0.0f, b1 = 0.0f;
        DSTEP(0,  a0, a1, b0, b1) DSTEP(1,  a0, a1, b0, b1)
        DSTEP(2,  a0, a1, b0, b1) DSTEP(3,  a0, a1, b0, b1)
        DSTEP(4,  a0, a1, b0, b1) DSTEP(5,  a0, a1, b0, b1)
        DSTEP(6,  a0, a1, b0, b1) DSTEP(7,  a0, a1, b0, b1)
        DSTEP(8,  a0, a1, b0, b1) DSTEP(9,  a0, a1, b0, b1)
        DSTEP(10, a0, a1, b0, b1) DSTEP(11, a0, a1, b0, b1)
        DSTEP(12, a0, a1, b0, b1) DSTEP(13, a0, a1, b0, b1)
        DSTEP(14, a0, a1, b0, b1) DSTEP(15, a0, a1, b0, b1)
        float v0 = a0 + b0, v1 = a1 + b1;
        // fused activation (wave-uniform branch: waves 4-5 are 'g')
        if (gtype == 2) { v0 = tanhf_(v0);    v1 = tanhf_(v1);    }
        else            { v0 = sigmoidf_(v0); v1 = sigmoidf_(v1); }
        g_lds[0][tid] = v0;
        g_lds[1][tid] = v1;
        __syncthreads();   // gates visible; all h reads done

        if (tid < 256) {
            int b = tid >> 7, j = tid & 127;
            float gi = g_lds[b][j];
            float gf = g_lds[b][128 + j];
            float gg = g_lds[b][256 + j];
            float go = g_lds[b][384 + j];
            cc = gf * cc + gi * gg;
            float h = go * tanhf_(cc);
            h_h[b][j] = f2h(h);
            if (j == 127)
                lasth[((size_t)kcls * 64 + bbase + b) * 256 + t] = h;
        }
        __syncthreads();   // new h visible
    }
#undef DSTEP
}

// ---------------- Kernel 5: gated mean over classes + output projection
__global__ __launch_bounds__(256) void k_out(
    const float* __restrict__ lasth, const float* __restrict__ S,
    const float* __restrict__ out_w, const float* __restrict__ out_b,
    float* __restrict__ out)
{
    __shared__ __align__(16) float avg[256];
    int b = blockIdx.x, t = threadIdx.x;
    float a = 0.f;
    #pragma unroll
    for (int k = 0; k < 8; ++k) {
        // pre.reshape(NCLS,B,1): weight(k,b) = S_flat[k*64+b]
        a = fmaf(S[k * 64 + b], lasth[((size_t)k * 64 + b) * 256 + t], a);
    }
    avg[t] = a * 0.125f;
    __syncthreads();
    if (t < 8) {
        float acc = out_b[t];
        for (int tt = 0; tt < 256; ++tt)
            acc = fmaf(avg[tt], out_w[t * 256 + tt], acc);
        out[b * 8 + t] = acc;
    }
}

extern "C" void kernel_launch(void* const* d_in, const int* in_sizes, int n_in,
                              void* d_out, int out_size, void* d_ws, size_t ws_size,
                              hipStream_t stream) {
    const float* x       = (const float*)d_in[0];
    const float* conv1_w = (const float*)d_in[1];
    const float* conv1_b = (const float*)d_in[2];
    const float* bn1_g   = (const float*)d_in[3];
    const float* bn1_b   = (const float*)d_in[4];
    const float* bn1_m   = (const float*)d_in[5];
    const float* bn1_v   = (const float*)d_in[6];
    const float* conv2_w = (const float*)d_in[7];
    const float* conv2_b = (const float*)d_in[8];
    const float* bn2_g   = (const float*)d_in[9];
    const float* bn2_b   = (const float*)d_in[10];
    const float* bn2_m   = (const float*)d_in[11];
    const float* bn2_v   = (const float*)d_in[12];
    const float* pre_w1  = (const float*)d_in[13];
    const float* pre_b1  = (const float*)d_in[14];
    const float* pre_w2  = (const float*)d_in[15];
    const float* pre_b2  = (const float*)d_in[16];
    const float* pre_w3  = (const float*)d_in[17];
    const float* pre_b3  = (const float*)d_in[18];
    const float* lstm_wih = (const float*)d_in[19];
    const float* lstm_whh = (const float*)d_in[20];
    const float* lstm_bih = (const float*)d_in[21];
    const float* lstm_bhh = (const float*)d_in[22];
    const float* hn      = (const float*)d_in[23];
    const float* out_w   = (const float*)d_in[24];
    const float* out_b   = (const float*)d_in[25];

    float* ws    = (float*)d_ws;
    float* c1    = ws;                       // 64*16*64*64 = 4194304 floats
    float* c     = c1 + 4194304;             // 64*256
    float* S     = c + 16384;                // 64*8
    float* lasth = S + 512;                  // 8*64*256
    // whh_h reuses the (already consumed) c1 region: 262144 uints = 1 MB.
    unsigned int* whh_h = (unsigned int*)c1;

    k_conv1<<<1024, 256, 0, stream>>>(x, conv1_w, conv1_b, bn1_g, bn1_b, bn1_m, bn1_v, c1);
    k_conv2<<<64, 256, 0, stream>>>(c1, conv2_w, conv2_b, bn2_g, bn2_b, bn2_m, bn2_v, c);
    k_mlp<<<64, 64, 0, stream>>>(c, pre_w1, pre_b1, pre_w2, pre_b2, pre_w3, pre_b3, S);
    k_cvt<<<1024, 256, 0, stream>>>(lstm_whh, whh_h);   // after conv2: c1 region free
    k_lstm<<<256, 512, 0, stream>>>(whh_h, lstm_wih, lstm_bih, lstm_bhh, hn, c, lasth);
    k_out<<<64, 256, 0, stream>>>(lasth, S, out_w, out_b, (float*)d_out);
}